// Round 2
// baseline (277.585 us; speedup 1.0000x reference)
//
#include <hip/hip_runtime.h>

#define NT 256
#define NCOL 1116
#define NLEV 7

typedef float v2f __attribute__((ext_vector_type(2)));

static constexpr float DEC_LO[8] = {-0.010597401784997278f,  0.032883011666982945f,
                                     0.030841381835986965f, -0.18703481171888114f,
                                    -0.02798376941698385f,   0.6308807679295904f,
                                     0.7148465705525415f,    0.23037781330885523f};
static constexpr float DEC_HI[8] = {-0.23037781330885523f,   0.7148465705525415f,
                                    -0.6308807679295904f,   -0.02798376941698385f,
                                     0.18703481171888114f,   0.030841381835986965f,
                                    -0.032883011666982945f, -0.010597401784997278f};
static constexpr float REC_LO[8] = { 0.23037781330885523f,   0.7148465705525415f,
                                     0.6308807679295904f,   -0.02798376941698385f,
                                    -0.18703481171888114f,   0.030841381835986965f,
                                     0.032883011666982945f, -0.010597401784997278f};
static constexpr float REC_HI[8] = {-0.010597401784997278f, -0.032883011666982945f,
                                     0.030841381835986965f,  0.18703481171888114f,
                                    -0.02798376941698385f,  -0.6308807679295904f,
                                     0.7148465705525415f,   -0.23037781330885523f};

// approx length per level; detail[l] has length ALEN[l+1]
static constexpr int ALEN[8] = {1116, 561, 284, 145, 76, 41, 24, 15};
// even storage offsets for detail segments (sizes 561,284,145,76,41,24,15)
static constexpr int DOFF[7] = {0, 562, 846, 992, 1068, 1110, 1136};

static __device__ __forceinline__ float softf(float c, float t) {
    float m = fabsf(c) - t;
    return m > 0.0f ? copysignf(m, c) : 0.0f;
}

static __device__ __forceinline__ v2f vfma(float c, v2f v, v2f a) {
#if __has_builtin(__builtin_elementwise_fma)
    return __builtin_elementwise_fma((v2f){c, c}, v, a);
#else
    v2f r; r.x = fmaf(c, v.x, a.x); r.y = fmaf(c, v.y, a.y); return r;
#endif
}

// Forward DWT level: computes ca->nxt (soft-thresholded if LAST), cd->dp (thresholded).
// cur data offset is ≡2 mod 4 floats, so window start 4t-6 is 16B aligned.
template <int L, bool LAST>
static __device__ __forceinline__ void fwd_level(const float* cur, float* nxt, float* dp,
                                                 float thr, int tid) {
    constexpr int nout = ALEN[L + 1];
    constexpr int ntask = (nout + 1) / 2;   // 2 outputs per task
    for (int t = tid; t < ntask; t += NT) {
        const float* src = cur + 4 * t - 6;            // 16B aligned
        float4 w0 = *(const float4*)src;
        float4 w1 = *(const float4*)(src + 4);
        float4 w2 = *(const float4*)(src + 8);
        float w[12] = {w0.x, w0.y, w0.z, w0.w, w1.x, w1.y, w1.z, w1.w,
                       w2.x, w2.y, w2.z, w2.w};
        v2f lo = {0.f, 0.f}, hi = {0.f, 0.f};
#pragma unroll
        for (int s = 0; s < 8; ++s) {
            v2f v = {w[7 - s], w[9 - s]};   // inputs for outputs o=2t and o=2t+1
            lo = vfma(DEC_LO[s], v, lo);
            hi = vfma(DEC_HI[s], v, hi);
        }
        if (LAST) { lo.x = softf(lo.x, thr); lo.y = softf(lo.y, thr); }
        hi.x = softf(hi.x, thr);
        hi.y = softf(hi.y, thr);
        // detail segments have >=1 slack after odd-length segments: unconditional ok
        *(v2f*)(dp + 2 * t) = hi;
        if (!(nout & 1) || (2 * t + 1 < nout)) {
            *(v2f*)(nxt + 2 * t) = lo;
        } else {
            nxt[2 * t] = lo.x;   // avoid racing with pad zeroing below
        }
    }
    if (!LAST) {
        // zero pads consumed by the next forward level (no race: main loop writes < nout)
        if (tid < 6) nxt[-6 + tid] = 0.0f;
        if (tid < 10) nxt[nout + tid] = 0.0f;
    }
}

// Inverse DWT level: 2 output pairs (4 samples) per task.
// y[2m]   = RL0*ca[m+3]+RL2*ca[m+2]+RL4*ca[m+1]+RL6*ca[m] + same with RH/cd
// y[2m+1] = RL1*ca[m+3]+RL3*ca[m+2]+RL5*ca[m+1]+RL7*ca[m] + same with RH/cd
template <int L, bool FINAL>
static __device__ __forceinline__ void inv_level(const float* ca, const float* dp,
                                                 float* y, int tid) {
    constexpr int M = ALEN[L + 1];
    constexpr int npair = M - 3;
    constexpr int ntask = (npair + 1) / 2;
    for (int t = tid; t < ntask; t += NT) {
        const float* cap = ca + 2 * t;
        const float* ddp = dp + 2 * t;
        float2 a01 = *(const float2*)cap;
        float2 a23 = *(const float2*)(cap + 2);
        float  a4  = cap[4];
        float2 d01 = *(const float2*)ddp;
        float2 d23 = *(const float2*)(ddp + 2);
        float  d4  = ddp[4];
        float aw[5] = {a01.x, a01.y, a23.x, a23.y, a4};
        float dw[5] = {d01.x, d01.y, d23.x, d23.y, d4};
        v2f ye = {0.f, 0.f}, yo = {0.f, 0.f};
#pragma unroll
        for (int k = 0; k < 4; ++k) {
            v2f va = {aw[3 - k], aw[4 - k]};  // ca[m+3-k] for m=2t, 2t+1
            v2f vd = {dw[3 - k], dw[4 - k]};
            ye = vfma(REC_LO[2 * k],     va, ye);
            yo = vfma(REC_LO[2 * k + 1], va, yo);
            ye = vfma(REC_HI[2 * k],     vd, ye);
            yo = vfma(REC_HI[2 * k + 1], vd, yo);
        }
        if (FINAL) {
            // npair=558 even: every task full; global addr 16B aligned
            *(float4*)(y + 4 * t) = make_float4(ye.x, yo.x, ye.y, yo.y);
        } else {
            // writes beyond 2*npair land in slack, values unused after barrier
            *(v2f*)(y + 4 * t)     = (v2f){ye.x, yo.x};
            *(v2f*)(y + 4 * t + 2) = (v2f){ye.y, yo.y};
        }
    }
}

__global__ __launch_bounds__(NT)
void wavelet_kernel(const float* __restrict__ x,
                    const float* __restrict__ thr_ptr,
                    float* __restrict__ out) {
    __shared__ __align__(16) float A[1136];  // 6 pre | 1116 | 10+ post
    __shared__ __align__(16) float B[580];   // 6 pre | up to 564 | post
    __shared__ __align__(16) float D[1154];  // thresholded details + slack

    const int tid = threadIdx.x;
    const float thr = fmaxf(thr_ptr[0], 0.01f);
    float* a0 = A + 6;   // data start ≡ 2 (mod 4) floats
    float* b0 = B + 6;

    // load row: global float4 -> two 8B LDS writes (data start misaligned by 8B)
    {
        const float4* xr = (const float4*)(x + (size_t)blockIdx.x * NCOL);
        for (int i = tid; i < NCOL / 4; i += NT) {
            float4 v = xr[i];
            *(v2f*)(a0 + 4 * i)     = (v2f){v.x, v.y};
            *(v2f*)(a0 + 4 * i + 2) = (v2f){v.z, v.w};
        }
        if (tid < 6)  A[tid] = 0.0f;
        if (tid < 10) a0[NCOL + tid] = 0.0f;
    }
    __syncthreads();

    fwd_level<0, false>(a0, b0, D + DOFF[0], thr, tid); __syncthreads();
    fwd_level<1, false>(b0, a0, D + DOFF[1], thr, tid); __syncthreads();
    fwd_level<2, false>(a0, b0, D + DOFF[2], thr, tid); __syncthreads();
    fwd_level<3, false>(b0, a0, D + DOFF[3], thr, tid); __syncthreads();
    fwd_level<4, false>(a0, b0, D + DOFF[4], thr, tid); __syncthreads();
    fwd_level<5, false>(b0, a0, D + DOFF[5], thr, tid); __syncthreads();
    fwd_level<6, true >(a0, b0, D + DOFF[6], thr, tid); __syncthreads();  // a7 in b0, thresholded

    inv_level<6, false>(b0, D + DOFF[6], a0, tid); __syncthreads();
    inv_level<5, false>(a0, D + DOFF[5], b0, tid); __syncthreads();
    inv_level<4, false>(b0, D + DOFF[4], a0, tid); __syncthreads();
    inv_level<3, false>(a0, D + DOFF[3], b0, tid); __syncthreads();
    inv_level<2, false>(b0, D + DOFF[2], a0, tid); __syncthreads();
    inv_level<1, false>(a0, D + DOFF[1], b0, tid); __syncthreads();

    float* orow = out + (size_t)blockIdx.x * NCOL;
    inv_level<0, true>(b0, D + DOFF[0], orow, tid);
}

extern "C" void kernel_launch(void* const* d_in, const int* in_sizes, int n_in,
                              void* d_out, int out_size, void* d_ws, size_t ws_size,
                              hipStream_t stream) {
    const float* x = (const float*)d_in[0];
    const float* thr = (const float*)d_in[1];
    float* out = (float*)d_out;
    const int nrow = in_sizes[0] / NCOL;
    hipLaunchKernelGGL(wavelet_kernel, dim3(nrow), dim3(NT), 0, stream, x, thr, out);
}